// Round 1
// baseline (127.648 us; speedup 1.0000x reference)
//
#include <hip/hip_runtime.h>

// Block-diagonal equivariant linear: 256x0e + 256x1o + 128x2e, B=32768, DIM=1664.
// Strategy: bf16 MFMA (memory-bound; fp32 VALU would be compute-bound at ~143us).
//  - prep_w: fp32 W -> scaled bf16 in MFMA B-fragment order in d_ws (576KB, L2-hot)
//  - linear_main: per-block batch tile, contiguous fp32 x loads, convert+deinterleave
//    into padded LDS, mfma_f32_16x16x32_bf16, direct fp32 stores.

typedef short short8 __attribute__((ext_vector_type(8)));
typedef float f32x4 __attribute__((ext_vector_type(4)));

#define DIMF 1664
#define KB 64
#define LDA 72  // KB + 8 shorts pad: row stride 144B -> 4-bank step -> 2-way conflict (free)

__device__ __forceinline__ unsigned short f2bf(float f) {
  // round-to-nearest-even fp32 -> bf16 (inputs are finite gaussians; no NaN path needed)
  unsigned int u = __float_as_uint(f);
  u += 0x7fffu + ((u >> 16) & 1u);
  return (unsigned short)(u >> 16);
}

// ws layout per segment: W[u][w] row-major, contraction over u (k), output col w (n).
// Fragment order: element ((nt*NKS + ks)*64 + lane)*8 + j  holds
//   W[k = ks*32 + (lane>>4)*8 + j][n = nt*16 + (lane&15)] * scale   as bf16.
__global__ __launch_bounds__(256) void prep_w(const float* __restrict__ ws,
                                              unsigned short* __restrict__ wf) {
  int t = blockIdx.x * blockDim.x + threadIdx.x;  // group index, 8 bf16 per group
  int MUL, woff, goff;
  float scale;
  if (t < 8192) {
    MUL = 256; woff = 0; goff = 0; scale = 0.0625f;
  } else if (t < 16384) {
    MUL = 256; woff = 65536; goff = 8192; scale = 0.0625f;
  } else if (t < 18432) {
    MUL = 128; woff = 131072; goff = 16384; scale = 0.088388347648318447f;  // 1/sqrt(128)
  } else {
    return;
  }
  int g = t - goff;
  int l = g & 63;
  int nks = MUL >> 5;             // k-steps of 32
  int ks = (g >> 6) % nks;
  int nt = g / (64 * nks);
  int n = nt * 16 + (l & 15);
  int kb = ks * 32 + (l >> 4) * 8;
  short8 v;
#pragma unroll
  for (int j = 0; j < 8; ++j)
    v[j] = (short)f2bf(ws[woff + (size_t)(kb + j) * MUL + n] * scale);
  *reinterpret_cast<short8*>(wf + (size_t)t * 8) = v;  // coalesced 16B stores
}

template <int MUL, int D, int BMB, bool BIAS>
__device__ __forceinline__ void gemm_seg(const float* __restrict__ x,
                                         const unsigned short* __restrict__ wf,
                                         const float* __restrict__ bs,
                                         float* __restrict__ out, int blk, int s,
                                         unsigned short* A_lds) {
  constexpr int MT = BMB * D;     // A_eff rows in tile (64 / 48 / 80)
  constexpr int NMT = MT / 16;    // m-tiles (4 / 3 / 5)
  constexpr int NTW = MUL / 64;   // n-tiles per wave, 4 waves (4 / 4 / 2)
  constexpr int NKS = MUL / 32;   // total 32-wide k-steps
  constexpr int NCH = MUL / KB;   // K chunks (4 / 4 / 2)
  constexpr int KBD = KB * D;     // contiguous floats per row per chunk

  const int tid = threadIdx.x;
  const int lane = tid & 63;
  const int wave = tid >> 6;
  const int l15 = lane & 15;
  const int lhi = lane >> 4;
  const int b0 = blk * BMB;

  f32x4 acc[NMT][NTW];
#pragma unroll
  for (int a = 0; a < NMT; ++a)
#pragma unroll
    for (int b = 0; b < NTW; ++b) acc[a][b] = (f32x4){0.f, 0.f, 0.f, 0.f};

  for (int ch = 0; ch < NCH; ++ch) {
    // --- stage A chunk: BMB rows x KBD contiguous floats -> bf16 deinterleaved LDS ---
    {
      int idx = tid;
#pragma unroll
      for (int it = 0; it < (BMB * KBD / 4) / 256; ++it, idx += 256) {
        int r = idx / (KBD / 4);
        int c4 = idx % (KBD / 4);
        f32x4 v = *reinterpret_cast<const f32x4*>(
            x + (size_t)(b0 + r) * DIMF + s + ch * KBD + c4 * 4);
#pragma unroll
        for (int j = 0; j < 4; ++j) {
          int col = c4 * 4 + j;   // within-chunk (u,i) flat index, u-major
          int u = col / D;
          int i = col - u * D;
          A_lds[(r * D + i) * LDA + u] = f2bf(v[j]);
        }
      }
    }
    __syncthreads();
    // --- MFMA over this chunk ---
#pragma unroll
    for (int ks = 0; ks < KB / 32; ++ks) {
      short8 af[NMT];
#pragma unroll
      for (int mt = 0; mt < NMT; ++mt)
        af[mt] = *reinterpret_cast<const short8*>(
            &A_lds[(mt * 16 + l15) * LDA + ks * 32 + lhi * 8]);
      int ksg = ch * (KB / 32) + ks;
#pragma unroll
      for (int nt = 0; nt < NTW; ++nt) {
        int ntg = wave * NTW + nt;
        short8 bfr = *reinterpret_cast<const short8*>(
            wf + ((size_t)(ntg * NKS + ksg) * 64 + lane) * 8);
#pragma unroll
        for (int mt = 0; mt < NMT; ++mt)
          acc[mt][nt] =
              __builtin_amdgcn_mfma_f32_16x16x32_bf16(af[mt], bfr, acc[mt][nt], 0, 0, 0);
      }
    }
    __syncthreads();
  }

  // --- epilogue: C/D layout col = lane&15, row = (lane>>4)*4 + q ---
#pragma unroll
  for (int nt = 0; nt < NTW; ++nt) {
    int n = wave * (MUL / 4) + nt * 16 + l15;
    float bias = 0.f;
    if (BIAS) bias = bs[n];
#pragma unroll
    for (int mt = 0; mt < NMT; ++mt) {
#pragma unroll
      for (int q = 0; q < 4; ++q) {
        int m = mt * 16 + lhi * 4 + q;
        int b = m / D;
        int i = m - b * D;
        out[(size_t)(b0 + b) * DIMF + s + n * D + i] = acc[mt][nt][q] + bias;
      }
    }
  }
}

__global__ __launch_bounds__(256) void linear_main(const float* __restrict__ x,
                                                   const unsigned short* __restrict__ wf,
                                                   const float* __restrict__ bs,
                                                   float* __restrict__ out) {
  __shared__ unsigned short A_lds[80 * LDA];  // max over segments (seg2: 80 rows)
  int blk = blockIdx.x;
  if (blk < 512) {
    gemm_seg<256, 1, 64, true>(x, wf, bs, out, blk, 0, A_lds);
  } else if (blk < 2560) {
    gemm_seg<256, 3, 16, false>(x, wf + 65536, bs, out, blk - 512, 256, A_lds);
  } else {
    gemm_seg<128, 5, 16, false>(x, wf + 131072, bs, out, blk - 2560, 1024, A_lds);
  }
}

extern "C" void kernel_launch(void* const* d_in, const int* in_sizes, int n_in,
                              void* d_out, int out_size, void* d_ws, size_t ws_size,
                              hipStream_t stream) {
  const float* ws = (const float*)d_in[0];  // 147456
  const float* bs = (const float*)d_in[1];  // 256
  const float* x = (const float*)d_in[2];   // 32768 x 1664
  float* out = (float*)d_out;
  unsigned short* wf = (unsigned short*)d_ws;  // 294912 bf16 = 576KB

  hipLaunchKernelGGL(prep_w, dim3(72), dim3(256), 0, stream, ws, wf);
  hipLaunchKernelGGL(linear_main, dim3(512 + 2048 + 2048), dim3(256), 0, stream, x, wf,
                     bs, out);
}

// Round 2
// 120.452 us; speedup vs baseline: 1.0597x; 1.0597x over previous
//
#include <hip/hip_runtime.h>

// Block-diagonal equivariant linear: 256x0e + 256x1o + 128x2e, B=32768, DIM=1664.
// bf16 MFMA, memory/latency-oriented structure:
//  - prep_w: fp32 W -> scaled bf16 in MFMA B-fragment order in d_ws (L2-hot)
//  - linear_main: one block = one batch tile, FULL K staged to LDS once
//    (single __syncthreads per block), wide ds_write_b64 deinterleave,
//    mfma_f32_16x16x32_bf16, direct fp32 stores from accumulator regs.

typedef short short8 __attribute__((ext_vector_type(8)));
typedef short short4v __attribute__((ext_vector_type(4)));
typedef float f32x4 __attribute__((ext_vector_type(4)));

#define DIMF 1664

__device__ __forceinline__ unsigned short f2bf(float f) {
  // round-to-nearest-even fp32 -> bf16 (finite gaussian inputs; no NaN path)
  unsigned int u = __float_as_uint(f);
  u += 0x7fffu + ((u >> 16) & 1u);
  return (unsigned short)(u >> 16);
}

// ws layout per segment: W[u][w] row-major; contraction over u (k), output col w (n).
// Fragment order: element ((nt*NKS + ks)*64 + lane)*8 + j holds
//   W[k = ks*32 + (lane>>4)*8 + j][n = nt*16 + (lane&15)] * scale  as bf16.
__global__ __launch_bounds__(256) void prep_w(const float* __restrict__ ws,
                                              unsigned short* __restrict__ wf) {
  int t = blockIdx.x * blockDim.x + threadIdx.x;  // group index, 8 bf16 per group
  int MUL, woff, goff;
  float scale;
  if (t < 8192) {
    MUL = 256; woff = 0; goff = 0; scale = 0.0625f;
  } else if (t < 16384) {
    MUL = 256; woff = 65536; goff = 8192; scale = 0.0625f;
  } else if (t < 18432) {
    MUL = 128; woff = 131072; goff = 16384; scale = 0.088388347648318447f;  // 1/sqrt(128)
  } else {
    return;
  }
  int g = t - goff;
  int l = g & 63;
  int nks = MUL >> 5;
  int ks = (g >> 6) % nks;
  int nt = g / (64 * nks);
  int n = nt * 16 + (l & 15);
  int kb = ks * 32 + (l >> 4) * 8;
  short8 v;
#pragma unroll
  for (int j = 0; j < 8; ++j)
    v[j] = (short)f2bf(ws[woff + (size_t)(kb + j) * MUL + n] * scale);
  *reinterpret_cast<short8*>(wf + (size_t)t * 8) = v;
}

// LDS tile: A_lds[row][u], row = local_b*D + i, padded row stride LDA (u16).
// LDA = MUL + 8 -> row stride 528B/272B = 4-bank step: <=2-way conflicts (free).
template <int MUL, int D, int BMB, bool BIAS>
__device__ __forceinline__ void gemm_seg(const float* __restrict__ x,
                                         const unsigned short* __restrict__ wf,
                                         const float* __restrict__ bs,
                                         float* __restrict__ out, int blk, int s,
                                         unsigned short* A_lds) {
  constexpr int LDA = MUL + 8;
  constexpr int MT = BMB * D;      // A rows in tile (32 / 48 / 80)
  constexpr int NMT = MT / 16;     // m-tiles (2 / 3 / 5)
  constexpr int NTW = MUL / 64;    // n-tiles per wave, 4 waves (4 / 4 / 2)
  constexpr int NKS = MUL / 32;    // 32-wide k-steps (8 / 8 / 4)
  constexpr int QPR = MUL / 4;     // quanta per batch row (4 u's x D i's each)
  constexpr int NQ = BMB * QPR / 256;  // quanta per thread (8 / 4 / 2)

  const int tid = threadIdx.x;
  const int lane = tid & 63;
  const int wave = tid >> 6;
  const int l15 = lane & 15;
  const int lhi = lane >> 4;
  const int b0 = blk * BMB;

  // ---- stage: full K extent, quanta of 4D consecutive floats ----
  {
    int g = tid;
#pragma unroll
    for (int it = 0; it < NQ; ++it, g += 256) {
      int r = g / QPR;
      int q = g - r * QPR;
      const float* src = x + (size_t)(b0 + r) * DIMF + s + q * 4 * D;
      f32x4 v[D];
#pragma unroll
      for (int jd = 0; jd < D; ++jd)
        v[jd] = reinterpret_cast<const f32x4*>(src)[jd];
#pragma unroll
      for (int i = 0; i < D; ++i) {
        short4v p;
#pragma unroll
        for (int up = 0; up < 4; ++up) {
          int j = up * D + i;  // compile-time after unroll
          p[up] = (short)f2bf(v[j >> 2][j & 3]);
        }
        *reinterpret_cast<short4v*>(&A_lds[(r * D + i) * LDA + q * 4]) = p;
      }
    }
  }
  __syncthreads();  // the only barrier in the block

  // ---- MFMA over full K ----
  f32x4 acc[NMT][NTW];
#pragma unroll
  for (int a = 0; a < NMT; ++a)
#pragma unroll
    for (int b = 0; b < NTW; ++b) acc[a][b] = (f32x4){0.f, 0.f, 0.f, 0.f};

  for (int ks = 0; ks < NKS; ++ks) {
    short8 af[NMT];
#pragma unroll
    for (int mt = 0; mt < NMT; ++mt)
      af[mt] = *reinterpret_cast<const short8*>(
          &A_lds[(mt * 16 + l15) * LDA + ks * 32 + lhi * 8]);
#pragma unroll
    for (int nt = 0; nt < NTW; ++nt) {
      int ntg = wave * NTW + nt;
      short8 bfr = *reinterpret_cast<const short8*>(
          wf + ((size_t)(ntg * NKS + ks) * 64 + lane) * 8);
#pragma unroll
      for (int mt = 0; mt < NMT; ++mt)
        acc[mt][nt] =
            __builtin_amdgcn_mfma_f32_16x16x32_bf16(af[mt], bfr, acc[mt][nt], 0, 0, 0);
    }
  }

  // ---- epilogue: C/D layout col = lane&15, row = (lane>>4)*4 + q ----
#pragma unroll
  for (int nt = 0; nt < NTW; ++nt) {
    int n = wave * (MUL / 4) + nt * 16 + l15;
    float bias = 0.f;
    if (BIAS) bias = bs[n];
#pragma unroll
    for (int mt = 0; mt < NMT; ++mt) {
#pragma unroll
      for (int q = 0; q < 4; ++q) {
        int m = mt * 16 + lhi * 4 + q;
        int b = m / D;
        int i = m - b * D;
        out[(size_t)(b0 + b) * DIMF + s + n * D + i] = acc[mt][nt][q] + bias;
      }
    }
  }
}

__global__ __launch_bounds__(256) void linear_main(const float* __restrict__ x,
                                                   const unsigned short* __restrict__ wf,
                                                   const float* __restrict__ bs,
                                                   float* __restrict__ out) {
  // max over segments: seg1 48 rows x 264 = 12672 u16 = 25344 B
  __shared__ unsigned short A_lds[48 * 264];
  int blk = blockIdx.x;
  if (blk < 1024) {
    gemm_seg<256, 1, 32, true>(x, wf, bs, out, blk, 0, A_lds);
  } else if (blk < 3072) {
    gemm_seg<256, 3, 16, false>(x, wf + 65536, bs, out, blk - 1024, 256, A_lds);
  } else {
    gemm_seg<128, 5, 16, false>(x, wf + 131072, bs, out, blk - 3072, 1024, A_lds);
  }
}

extern "C" void kernel_launch(void* const* d_in, const int* in_sizes, int n_in,
                              void* d_out, int out_size, void* d_ws, size_t ws_size,
                              hipStream_t stream) {
  const float* ws = (const float*)d_in[0];  // 147456
  const float* bs = (const float*)d_in[1];  // 256
  const float* x = (const float*)d_in[2];   // 32768 x 1664
  float* out = (float*)d_out;
  unsigned short* wf = (unsigned short*)d_ws;  // 294912 bf16 = 576KB

  hipLaunchKernelGGL(prep_w, dim3(72), dim3(256), 0, stream, ws, wf);
  hipLaunchKernelGGL(linear_main, dim3(1024 + 2048 + 2048), dim3(256), 0, stream, x,
                     wf, bs, out);
}